// Round 1
// baseline (414.994 us; speedup 1.0000x reference)
//
#include <hip/hip_runtime.h>
#include <math.h>

// Problem constants (match reference: B,S,D,V,N_BLOCKS = 4096,128,9,5,4)
constexpr int Bn = 4096;
constexpr int Sn = 128;
constexpr int Dn = 9;
constexpr int Vn = 5;
constexpr int NBn = 4;

// One 64-thread wave per batch. Thread t owns sequence rows {t, t+64}.
// x, Q, and attention state in registers; only K/V staged in LDS
// (rows stride 12 floats = 48B, 16B-aligned for ds_read_b128 broadcasts).
__global__ __launch_bounds__(64) void bert_kernel(
    const int*   __restrict__ tokens,
    const float* __restrict__ emb,
    const float* __restrict__ Wq, const float* __restrict__ bq,
    const float* __restrict__ Wk, const float* __restrict__ bk,
    const float* __restrict__ Wv, const float* __restrict__ bv,
    const float* __restrict__ Wout, const float* __restrict__ bout,
    float*       __restrict__ out)
{
    __shared__ float Ks[Sn][12];
    __shared__ float Vs[Sn][12];

    const int b = blockIdx.x;
    const int t = threadIdx.x;   // 0..63
    const float scale = 1.0f / 3.0f;

    // 10000^(-2*(d/2)/9), d=0..8 (pos-encoding inverse frequencies)
    const float inv_freq[Dn] = {
        1.0f, 1.0f,
        0.1291549665f, 0.1291549665f,
        0.0166810054f, 0.0166810054f,
        0.0021544347f, 0.0021544347f,
        0.0002782559f
    };

    // ---- embed + positional encoding (rows t, t+64) -> registers ----
    float x0[Dn], x1[Dn];
    {
        const int tok0 = tokens[b * Sn + t];
        const int tok1 = tokens[b * Sn + t + 64];
        #pragma unroll
        for (int d = 0; d < Dn; ++d) {
            const float a0 = (float)t * inv_freq[d];
            const float a1 = (float)(t + 64) * inv_freq[d];
            const float p0 = (d & 1) ? cosf(a0) : sinf(a0);
            const float p1 = (d & 1) ? cosf(a1) : sinf(a1);
            x0[d] = emb[tok0 * Dn + d] + p0;
            x1[d] = emb[tok1 * Dn + d] + p1;
        }
    }

    #pragma unroll 1
    for (int it = 0; it < NBn; ++it) {
        const float* wq  = Wq + it * 81;
        const float* wk  = Wk + it * 81;
        const float* wv  = Wv + it * 81;
        const float* bqi = bq + it * 9;
        const float* bki = bk + it * 9;
        const float* bvi = bv + it * 9;

        // ---- phase 1: Q -> regs, K/V -> LDS ----
        float q0[Dn], q1[Dn];
        __syncthreads();   // prior-iter phase-2 reads done before overwrite
        #pragma unroll
        for (int e = 0; e < Dn; ++e) {
            float aq0 = bqi[e], aq1 = bqi[e];
            float ak0 = bki[e], ak1 = bki[e];
            float av0 = bvi[e], av1 = bvi[e];
            #pragma unroll
            for (int d = 0; d < Dn; ++d) {
                const float wqe = wq[e * 9 + d];
                const float wke = wk[e * 9 + d];
                const float wve = wv[e * 9 + d];
                aq0 += x0[d] * wqe;  aq1 += x1[d] * wqe;
                ak0 += x0[d] * wke;  ak1 += x1[d] * wke;
                av0 += x0[d] * wve;  av1 += x1[d] * wve;
            }
            q0[e] = aq0;  q1[e] = aq1;
            Ks[t][e] = ak0;       Ks[t + 64][e] = ak1;
            Vs[t][e] = av0;       Vs[t + 64][e] = av1;
        }
        __syncthreads();

        // ---- phase 2: fused scores -> online softmax -> PV ----
        float m0 = -1e30f, l0 = 0.0f;
        float m1 = -1e30f, l1 = 0.0f;
        float o0[Dn], o1[Dn];
        #pragma unroll
        for (int d = 0; d < Dn; ++d) { o0[d] = 0.0f; o1[d] = 0.0f; }

        for (int k0 = 0; k0 < Sn; k0 += 8) {
            float s0[8], s1[8];
            #pragma unroll
            for (int j = 0; j < 8; ++j) {
                const float* kr = &Ks[k0 + j][0];   // wave-uniform -> broadcast
                float a0 = 0.0f, a1 = 0.0f;
                #pragma unroll
                for (int d = 0; d < Dn; ++d) {
                    const float kv = kr[d];
                    a0 += q0[d] * kv;
                    a1 += q1[d] * kv;
                }
                s0[j] = a0 * scale;
                s1[j] = a1 * scale;
            }
            float cm0 = s0[0], cm1 = s1[0];
            #pragma unroll
            for (int j = 1; j < 8; ++j) { cm0 = fmaxf(cm0, s0[j]); cm1 = fmaxf(cm1, s1[j]); }
            const float nm0 = fmaxf(m0, cm0), nm1 = fmaxf(m1, cm1);
            const float al0 = __expf(m0 - nm0), al1 = __expf(m1 - nm1);
            float ps0 = 0.0f, ps1 = 0.0f;
            #pragma unroll
            for (int j = 0; j < 8; ++j) {
                s0[j] = __expf(s0[j] - nm0); ps0 += s0[j];
                s1[j] = __expf(s1[j] - nm1); ps1 += s1[j];
            }
            l0 = l0 * al0 + ps0;  l1 = l1 * al1 + ps1;
            m0 = nm0;             m1 = nm1;
            #pragma unroll
            for (int d = 0; d < Dn; ++d) { o0[d] *= al0; o1[d] *= al1; }
            #pragma unroll
            for (int j = 0; j < 8; ++j) {
                const float* vr = &Vs[k0 + j][0];   // broadcast
                #pragma unroll
                for (int d = 0; d < Dn; ++d) {
                    const float vv = vr[d];
                    o0[d] += s0[j] * vv;
                    o1[d] += s1[j] * vv;
                }
            }
        }
        const float r0 = 1.0f / l0, r1 = 1.0f / l1;
        #pragma unroll
        for (int d = 0; d < Dn; ++d) { x0[d] = o0[d] * r0; x1[d] = o1[d] * r1; }
    }

    // ---- logits + log_softmax ----
    #pragma unroll
    for (int rr = 0; rr < 2; ++rr) {
        const float* xr = rr ? x1 : x0;
        const int s = t + rr * 64;
        float lg[Vn];
        #pragma unroll
        for (int v = 0; v < Vn; ++v) {
            float a = bout[v];
            #pragma unroll
            for (int d = 0; d < Dn; ++d) a += xr[d] * Wout[v * Dn + d];
            lg[v] = a;
        }
        float mm = lg[0];
        #pragma unroll
        for (int v = 1; v < Vn; ++v) mm = fmaxf(mm, lg[v]);
        float sum = 0.0f;
        #pragma unroll
        for (int v = 0; v < Vn; ++v) sum += __expf(lg[v] - mm);
        const float lse = __logf(sum) + mm;
        float* op = out + ((size_t)b * Sn + s) * Vn;
        #pragma unroll
        for (int v = 0; v < Vn; ++v) op[v] = lg[v] - lse;
    }
}

extern "C" void kernel_launch(void* const* d_in, const int* in_sizes, int n_in,
                              void* d_out, int out_size, void* d_ws, size_t ws_size,
                              hipStream_t stream) {
    const int*   tokens = (const int*)  d_in[0];
    const float* emb    = (const float*)d_in[1];
    const float* Wq     = (const float*)d_in[2];
    const float* bq_    = (const float*)d_in[3];
    const float* Wk     = (const float*)d_in[4];
    const float* bk_    = (const float*)d_in[5];
    const float* Wv     = (const float*)d_in[6];
    const float* bv_    = (const float*)d_in[7];
    const float* Wout   = (const float*)d_in[8];
    const float* bout_  = (const float*)d_in[9];
    float* out = (float*)d_out;

    bert_kernel<<<dim3(Bn), dim3(64), 0, stream>>>(
        tokens, emb, Wq, bq_, Wk, bk_, Wv, bv_, Wout, bout_, out);
}

// Round 2
// 278.928 us; speedup vs baseline: 1.4878x; 1.4878x over previous
//
#include <hip/hip_runtime.h>
#include <math.h>

// B,S,D,V,N_BLOCKS = 4096,128,9,5,4
constexpr int Bn = 4096;
constexpr int Sn = 128;
constexpr int Dn = 9;
constexpr int Vn = 5;
constexpr int NBn = 4;
constexpr int WPB = 4;   // waves (=batches) per 256-thread block

typedef float f2 __attribute__((ext_vector_type(2)));

static __device__ __forceinline__ f2 splat(float v) { f2 r; r.x = v; r.y = v; return r; }

// One wave per batch; 4 waves per block. Thread t owns seq rows {t, t+64},
// packed as float2 so the backend emits v_pk_fma_f32 (2 FMA/lane/inst).
// Per-wave K/V staged in LDS, rows stride 12 floats (48B, b128-aligned);
// all K/V reads are wave-uniform broadcasts (conflict-free).
__global__ __launch_bounds__(256) void bert_kernel(
    const int*   __restrict__ tokens,
    const float* __restrict__ emb,
    const float* __restrict__ Wq, const float* __restrict__ bq,
    const float* __restrict__ Wk, const float* __restrict__ bk,
    const float* __restrict__ Wv, const float* __restrict__ bv,
    const float* __restrict__ Wout, const float* __restrict__ bout,
    float*       __restrict__ out)
{
    __shared__ float Ks[WPB][Sn][12];
    __shared__ float Vs[WPB][Sn][12];

    const int w = threadIdx.x >> 6;    // wave id = local batch
    const int t = threadIdx.x & 63;    // lane
    const int b = blockIdx.x * WPB + w;
    const float scale = 1.0f / 3.0f;

    const float inv_freq[Dn] = {
        1.0f, 1.0f,
        0.1291549665f, 0.1291549665f,
        0.0166810054f, 0.0166810054f,
        0.0021544347f, 0.0021544347f,
        0.0002782559f
    };

    // ---- embed + positional encoding: x[d] = {row t, row t+64} ----
    f2 x[Dn];
    {
        const int tok0 = tokens[b * Sn + t];
        const int tok1 = tokens[b * Sn + t + 64];
        #pragma unroll
        for (int d = 0; d < Dn; ++d) {
            const float a0 = (float)t * inv_freq[d];
            const float a1 = (float)(t + 64) * inv_freq[d];
            const float p0 = (d & 1) ? cosf(a0) : sinf(a0);
            const float p1 = (d & 1) ? cosf(a1) : sinf(a1);
            x[d].x = emb[tok0 * Dn + d] + p0;
            x[d].y = emb[tok1 * Dn + d] + p1;
        }
    }

    #pragma unroll 1
    for (int it = 0; it < NBn; ++it) {
        const float* wq  = Wq + it * 81;
        const float* wk  = Wk + it * 81;
        const float* wv  = Wv + it * 81;
        const float* bqi = bq + it * 9;
        const float* bki = bk + it * 9;
        const float* bvi = bv + it * 9;

        // ---- phase 1: Q (pre-scaled) -> regs, K/V -> LDS ----
        f2 q[Dn];
        __syncthreads();   // prior-iter phase-2 LDS reads done before overwrite
        #pragma unroll
        for (int e = 0; e < Dn; ++e) {
            f2 aq = splat(bqi[e]);
            f2 ak = splat(bki[e]);
            f2 av = splat(bvi[e]);
            #pragma unroll
            for (int d = 0; d < Dn; ++d) {
                aq = __builtin_elementwise_fma(x[d], splat(wq[e * 9 + d]), aq);
                ak = __builtin_elementwise_fma(x[d], splat(wk[e * 9 + d]), ak);
                av = __builtin_elementwise_fma(x[d], splat(wv[e * 9 + d]), av);
            }
            q[e] = aq * splat(scale);    // fold score scale into Q
            Ks[w][t][e] = ak.x;  Ks[w][t + 64][e] = ak.y;
            Vs[w][t][e] = av.x;  Vs[w][t + 64][e] = av.y;
        }
        __syncthreads();

        // ---- phase 2: fused scores -> online softmax -> PV (chunk=16) ----
        f2 m = splat(-1e30f), l = splat(0.0f);
        f2 o[Dn];
        #pragma unroll
        for (int d = 0; d < Dn; ++d) o[d] = splat(0.0f);

        #pragma unroll 1
        for (int k0 = 0; k0 < Sn; k0 += 16) {
            f2 s[16];
            #pragma unroll
            for (int j = 0; j < 16; ++j) {
                const float* kr = &Ks[w][k0 + j][0];   // wave-uniform broadcast
                f2 a = splat(0.0f);
                #pragma unroll
                for (int d = 0; d < Dn; ++d)
                    a = __builtin_elementwise_fma(q[d], splat(kr[d]), a);
                s[j] = a;
            }
            f2 cm = s[0];
            #pragma unroll
            for (int j = 1; j < 16; ++j) cm = __builtin_elementwise_max(cm, s[j]);
            const f2 nm = __builtin_elementwise_max(m, cm);
            f2 al;
            al.x = __expf(m.x - nm.x);
            al.y = __expf(m.y - nm.y);
            f2 ps = splat(0.0f);
            #pragma unroll
            for (int j = 0; j < 16; ++j) {
                s[j].x = __expf(s[j].x - nm.x);
                s[j].y = __expf(s[j].y - nm.y);
                ps += s[j];
            }
            l = l * al + ps;
            m = nm;
            #pragma unroll
            for (int d = 0; d < Dn; ++d) o[d] *= al;
            #pragma unroll
            for (int j = 0; j < 16; ++j) {
                const float* vr = &Vs[w][k0 + j][0];   // broadcast
                #pragma unroll
                for (int d = 0; d < Dn; ++d)
                    o[d] = __builtin_elementwise_fma(s[j], splat(vr[d]), o[d]);
            }
        }
        f2 r;
        r.x = 1.0f / l.x;
        r.y = 1.0f / l.y;
        #pragma unroll
        for (int d = 0; d < Dn; ++d) x[d] = o[d] * r;
    }

    // ---- logits + log_softmax (unpack the two rows) ----
    #pragma unroll
    for (int rr = 0; rr < 2; ++rr) {
        const int s = t + rr * 64;
        float xr[Dn];
        #pragma unroll
        for (int d = 0; d < Dn; ++d) xr[d] = rr ? x[d].y : x[d].x;
        float lg[Vn];
        #pragma unroll
        for (int v = 0; v < Vn; ++v) {
            float a = bout[v];
            #pragma unroll
            for (int d = 0; d < Dn; ++d) a += xr[d] * Wout[v * Dn + d];
            lg[v] = a;
        }
        float mm = lg[0];
        #pragma unroll
        for (int v = 1; v < Vn; ++v) mm = fmaxf(mm, lg[v]);
        float sum = 0.0f;
        #pragma unroll
        for (int v = 0; v < Vn; ++v) sum += __expf(lg[v] - mm);
        const float lse = __logf(sum) + mm;
        float* op = out + ((size_t)b * Sn + s) * Vn;
        #pragma unroll
        for (int v = 0; v < Vn; ++v) op[v] = lg[v] - lse;
    }
}

extern "C" void kernel_launch(void* const* d_in, const int* in_sizes, int n_in,
                              void* d_out, int out_size, void* d_ws, size_t ws_size,
                              hipStream_t stream) {
    const int*   tokens = (const int*)  d_in[0];
    const float* emb    = (const float*)d_in[1];
    const float* Wq     = (const float*)d_in[2];
    const float* bq_    = (const float*)d_in[3];
    const float* Wk     = (const float*)d_in[4];
    const float* bk_    = (const float*)d_in[5];
    const float* Wv     = (const float*)d_in[6];
    const float* bv_    = (const float*)d_in[7];
    const float* Wout   = (const float*)d_in[8];
    const float* bout_  = (const float*)d_in[9];
    float* out = (float*)d_out;

    bert_kernel<<<dim3(Bn / WPB), dim3(256), 0, stream>>>(
        tokens, emb, Wq, bq_, Wk, bk_, Wv, bv_, Wout, bout_, out);
}

// Round 3
// 224.269 us; speedup vs baseline: 1.8504x; 1.2437x over previous
//
#include <hip/hip_runtime.h>
#include <math.h>

// B,S,D,V,N_BLOCKS = 4096,128,9,5,4
constexpr int Bn = 4096;
constexpr int Sn = 128;
constexpr int Dn = 9;
constexpr int Vn = 5;
constexpr int NBn = 4;
constexpr int WPB = 2;   // waves (=batches) per 128-thread block

typedef float f2 __attribute__((ext_vector_type(2)));
typedef float f4 __attribute__((ext_vector_type(4)));

static __device__ __forceinline__ f2 splat(float v) { f2 r; r.x = v; r.y = v; return r; }

// One wave per batch; 2 waves per block (small LDS -> 7-8 blocks/CU).
// Thread t owns seq rows {t, t+64} packed as float2 (v_pk_fma_f32).
// K/V rows packed at stride 9 floats; read in aligned groups of 4 rows
// (144B = 9 x ds_read_b128, wave-uniform broadcast, conflict-free).
// Softmax in exp2 domain: log2(e)/sqrt(D) folded into Q.
__global__ __launch_bounds__(128, 4) void bert_kernel(
    const int*   __restrict__ tokens,
    const float* __restrict__ emb,
    const float* __restrict__ Wq, const float* __restrict__ bq,
    const float* __restrict__ Wk, const float* __restrict__ bk,
    const float* __restrict__ Wv, const float* __restrict__ bv,
    const float* __restrict__ Wout, const float* __restrict__ bout,
    float*       __restrict__ out)
{
    __shared__ __align__(16) float Ks[WPB][Sn * Dn];
    __shared__ __align__(16) float Vs[WPB][Sn * Dn];

    const int w = threadIdx.x >> 6;    // wave id = local batch
    const int t = threadIdx.x & 63;    // lane
    const int b = blockIdx.x * WPB + w;
    const float qscale = (1.0f / 3.0f) * 1.44269504f;   // 1/sqrt(D) * log2(e)

    const float inv_freq[Dn] = {
        1.0f, 1.0f,
        0.1291549665f, 0.1291549665f,
        0.0166810054f, 0.0166810054f,
        0.0021544347f, 0.0021544347f,
        0.0002782559f
    };

    // ---- embed + positional encoding: x[d] = {row t, row t+64} ----
    f2 x[Dn];
    {
        const int tok0 = tokens[b * Sn + t];
        const int tok1 = tokens[b * Sn + t + 64];
        #pragma unroll
        for (int d = 0; d < Dn; ++d) {
            const float a0 = (float)t * inv_freq[d];
            const float a1 = (float)(t + 64) * inv_freq[d];
            const float p0 = (d & 1) ? cosf(a0) : sinf(a0);
            const float p1 = (d & 1) ? cosf(a1) : sinf(a1);
            x[d].x = emb[tok0 * Dn + d] + p0;
            x[d].y = emb[tok1 * Dn + d] + p1;
        }
    }

    #pragma unroll 1
    for (int it = 0; it < NBn; ++it) {
        const float* wq  = Wq + it * 81;
        const float* wk  = Wk + it * 81;
        const float* wv  = Wv + it * 81;
        const float* bqi = bq + it * 9;
        const float* bki = bk + it * 9;
        const float* bvi = bv + it * 9;

        // ---- phase 1: Q (pre-scaled, log2 domain) -> regs, K/V -> LDS ----
        f2 q[Dn];
        __syncthreads();   // prior-iter phase-2 LDS reads done before overwrite
        #pragma unroll
        for (int e = 0; e < Dn; ++e) {
            f2 aq = splat(bqi[e]);
            f2 ak = splat(bki[e]);
            f2 av = splat(bvi[e]);
            #pragma unroll
            for (int d = 0; d < Dn; ++d) {
                aq = __builtin_elementwise_fma(x[d], splat(wq[e * 9 + d]), aq);
                ak = __builtin_elementwise_fma(x[d], splat(wk[e * 9 + d]), ak);
                av = __builtin_elementwise_fma(x[d], splat(wv[e * 9 + d]), av);
            }
            q[e] = aq * splat(qscale);
            Ks[w][Dn * t + e]        = ak.x;
            Ks[w][Dn * (t + 64) + e] = ak.y;
            Vs[w][Dn * t + e]        = av.x;
            Vs[w][Dn * (t + 64) + e] = av.y;
        }
        __syncthreads();

        // ---- phase 2: fused scores -> online softmax (exp2) -> PV ----
        f2 m = splat(-1e30f), l = splat(0.0f);
        f2 o[Dn];
        #pragma unroll
        for (int d = 0; d < Dn; ++d) o[d] = splat(0.0f);

        #pragma unroll 1
        for (int k0 = 0; k0 < Sn; k0 += 16) {
            f2 s[16];
            // scores: 4 groups of 4 rows; each group = 9 aligned b128 broadcasts
            #pragma unroll
            for (int g = 0; g < 4; ++g) {
                const f4* kp = (const f4*)&Ks[w][(k0 + 4 * g) * Dn];
                f4 kb[9];
                #pragma unroll
                for (int u = 0; u < 9; ++u) kb[u] = kp[u];
                const float* kf = (const float*)kb;   // 4 rows x 9 floats
                #pragma unroll
                for (int j = 0; j < 4; ++j) {
                    f2 a = splat(0.0f);
                    #pragma unroll
                    for (int d = 0; d < Dn; ++d)
                        a = __builtin_elementwise_fma(q[d], splat(kf[9 * j + d]), a);
                    s[4 * g + j] = a;
                }
            }
            f2 cm = s[0];
            #pragma unroll
            for (int j = 1; j < 16; ++j) cm = __builtin_elementwise_max(cm, s[j]);
            const f2 nm = __builtin_elementwise_max(m, cm);
            f2 al;
            al.x = __builtin_amdgcn_exp2f(m.x - nm.x);
            al.y = __builtin_amdgcn_exp2f(m.y - nm.y);
            f2 ps = splat(0.0f);
            #pragma unroll
            for (int j = 0; j < 16; ++j) {
                s[j].x = __builtin_amdgcn_exp2f(s[j].x - nm.x);
                s[j].y = __builtin_amdgcn_exp2f(s[j].y - nm.y);
                ps += s[j];
            }
            l = l * al + ps;
            m = nm;
            #pragma unroll
            for (int d = 0; d < Dn; ++d) o[d] *= al;
            // PV: same grouped broadcast of V rows
            #pragma unroll
            for (int g = 0; g < 4; ++g) {
                const f4* vp = (const f4*)&Vs[w][(k0 + 4 * g) * Dn];
                f4 vb[9];
                #pragma unroll
                for (int u = 0; u < 9; ++u) vb[u] = vp[u];
                const float* vf = (const float*)vb;
                #pragma unroll
                for (int j = 0; j < 4; ++j) {
                    const f2 pj = s[4 * g + j];
                    #pragma unroll
                    for (int d = 0; d < Dn; ++d)
                        o[d] = __builtin_elementwise_fma(pj, splat(vf[9 * j + d]), o[d]);
                }
            }
        }
        f2 r;
        r.x = 1.0f / l.x;
        r.y = 1.0f / l.y;
        #pragma unroll
        for (int d = 0; d < Dn; ++d) x[d] = o[d] * r;
    }

    // ---- logits + log_softmax (unpack the two rows) ----
    #pragma unroll
    for (int rr = 0; rr < 2; ++rr) {
        const int s = t + rr * 64;
        float xr[Dn];
        #pragma unroll
        for (int d = 0; d < Dn; ++d) xr[d] = rr ? x[d].y : x[d].x;
        float lg[Vn];
        #pragma unroll
        for (int v = 0; v < Vn; ++v) {
            float a = bout[v];
            #pragma unroll
            for (int d = 0; d < Dn; ++d) a += xr[d] * Wout[v * Dn + d];
            lg[v] = a;
        }
        float mm = lg[0];
        #pragma unroll
        for (int v = 1; v < Vn; ++v) mm = fmaxf(mm, lg[v]);
        float sum = 0.0f;
        #pragma unroll
        for (int v = 0; v < Vn; ++v)
            sum += __builtin_amdgcn_exp2f((lg[v] - mm) * 1.44269504f);
        const float lse = __builtin_amdgcn_logf(sum) * 0.69314718f + mm;
        float* op = out + ((size_t)b * Sn + s) * Vn;
        #pragma unroll
        for (int v = 0; v < Vn; ++v) op[v] = lg[v] - lse;
    }
}

extern "C" void kernel_launch(void* const* d_in, const int* in_sizes, int n_in,
                              void* d_out, int out_size, void* d_ws, size_t ws_size,
                              hipStream_t stream) {
    const int*   tokens = (const int*)  d_in[0];
    const float* emb    = (const float*)d_in[1];
    const float* Wq     = (const float*)d_in[2];
    const float* bq_    = (const float*)d_in[3];
    const float* Wk     = (const float*)d_in[4];
    const float* bk_    = (const float*)d_in[5];
    const float* Wv     = (const float*)d_in[6];
    const float* bv_    = (const float*)d_in[7];
    const float* Wout   = (const float*)d_in[8];
    const float* bout_  = (const float*)d_in[9];
    float* out = (float*)d_out;

    bert_kernel<<<dim3(Bn / WPB), dim3(128), 0, stream>>>(
        tokens, emb, Wq, bq_, Wk, bk_, Wv, bv_, Wout, bout_, out);
}